// Round 5
// baseline (251.536 us; speedup 1.0000x reference)
//
#include <hip/hip_runtime.h>
#include <stdint.h>

#define TT 512
#define BT 16   // 4096/16 = 256 wgs = 1 wg/CU

typedef float    f32x4 __attribute__((ext_vector_type(4)));
typedef float    f32x2 __attribute__((ext_vector_type(2)));
typedef short    s16x8 __attribute__((ext_vector_type(8)));
typedef _Float16 f16x8 __attribute__((ext_vector_type(8)));

#define MFMA_F16(A, B, C) \
    __builtin_amdgcn_mfma_f32_16x16x32_f16( \
        __builtin_bit_cast(f16x8, (A)), (B), (C), 0, 0, 0)

#define LOG2E  1.442695040888963f
#define LOG2E2 2.885390081777927f

// 512 threads = 8 waves. Waves w and w+4 mirror: identical MFMAs for hidden
// cols [16*(w&3), 16*(w&3)+16) (B-frags live in each wave's registers — MFMA
// pipe was only 13% busy, duplication is free), but each wave does only HALF
// the elementwise: wave w -> acc regs {0,1} (batches quad*4+{0,1}), wave w+4
// -> regs {2,3}. Total elementwise lane-work unchanged; 2 waves/SIMD hide the
// trans-pipe bursts and the LDS/barrier latency that a single wave exposes.
// fp16 MFMA (6/step/wave), W_hh in registers, h via LDS A-frag dbuf,
// 1 barrier/step. Bias vectors passed directly as MFMA C operand.
__global__ __launch_bounds__(512) void gru_scan_kernel(
    const float* __restrict__ x,     // (4096, 512, 1)
    const float* __restrict__ Wih,   // (192, 1)
    const float* __restrict__ Whh,   // (192, 64)
    const float* __restrict__ bih,   // (192)
    const float* __restrict__ bhh,   // (192)
    const float* __restrict__ Wout,  // (1, 64)
    const float* __restrict__ bout,  // (1)
    float* __restrict__ out)         // (4096, 1)
{
    __shared__ __align__(16) float xs2[TT * BT];     // x transposed [t][b], 32 KB
    // [dbuf][Kchunk][slot = kgroup*16 + m][8 f16] : A-frag order, 4 KB
    __shared__ __align__(16) short hbuf[2][2][64][8];
    __shared__ float outp[8][BT];

    const int tid  = threadIdx.x;
    const int wv   = tid >> 6;        // 0..7
    const int L    = tid & 63;
    const int n16  = L & 15;
    const int quad = L >> 4;
    const int colw = wv & 3;
    const int q    = colw * 16 + n16;     // hidden col owned by this lane
    const int rb   = (wv >> 2) * 2;       // elementwise regs rb, rb+1
    const int b0   = blockIdx.x * BT;

    // ---- stage x transposed: xs2[t][b] ----
    #pragma unroll
    for (int k = 0; k < 4; ++k) {
        int idx = tid + k * 512;          // 0..2047
        int row = idx >> 7;               // batch row 0..15
        int t4  = idx & 127;              // t/4
        f32x4 v = *(const f32x4*)(x + (size_t)(b0 + row) * TT + t4 * 4);
        #pragma unroll
        for (int i = 0; i < 4; ++i)
            xs2[(t4 * 4 + i) * BT + row] = v[i];
    }
    // ---- zero both h double-buffers (4 KB) ----
    if (tid < 256) {
        f32x4* hb = (f32x4*)hbuf;
        f32x4 zv = {0.f, 0.f, 0.f, 0.f};
        hb[tid] = zv;
    }

    // ---- per-lane constants (gate scales folded) ----
    const float wr2   = -LOG2E  * Wih[q];
    const float wz2   = -LOG2E  * Wih[64 + q];
    const float wn2   =  LOG2E2 * Wih[128 + q];
    const float bR2   = -LOG2E  * (bih[q]      + bhh[q]);
    const float bZ2   = -LOG2E  * (bih[64 + q] + bhh[64 + q]);
    const float bN2   =  LOG2E2 * bhh[128 + q];
    const float bihn2 =  LOG2E2 * bih[128 + q];
    const float wo    = Wout[q];

    const f32x4 bR4 = {bR2, bR2, bR2, bR2};
    const f32x4 bZ4 = {bZ2, bZ2, bZ2, bZ2};
    const f32x4 bN4 = {bN2, bN2, bN2, bN2};

    // ---- W_hh B-fragments (scaled), fp16 RNE ----
    f16x8 Bf[3][2];
    #pragma unroll
    for (int g = 0; g < 3; ++g) {
        const float sg = (g == 2) ? LOG2E2 : -LOG2E;
        #pragma unroll
        for (int c = 0; c < 2; ++c) {
            const float* p = Whh + ((g * 64 + q) * 64 + c * 32 + quad * 8);
            #pragma unroll
            for (int j = 0; j < 8; ++j)
                Bf[g][c][j] = (_Float16)(p[j] * sg);
        }
    }

    // persistent h (fp32) for this wave's 2 batches: m = quad*4 + rb + {0,1}
    float hD[2] = {0.f, 0.f};

    // writer-side A-layout address pieces for col q
    const int cw = q >> 5;           // K-chunk
    const int qd = (q & 31) >> 3;    // k-group
    const int jw = q & 7;            // element within group
    const int m0 = quad * 4 + rb;    // first batch row this wave updates

    const s16x8* hbv = (const s16x8*)hbuf;   // dbuf stride 128, chunk stride 64

    auto step = [&](int cur, int t) {
        __syncthreads();

        s16x8 A0 = hbv[cur * 128 +  0 + L];
        s16x8 A1 = hbv[cur * 128 + 64 + L];
        f32x2 xv2 = *(const f32x2*)(xs2 + t * BT + m0);  // 2 batches' x

        // r-gate first (its result heads the serial chain), z last
        f32x4 aR = MFMA_F16(A0, Bf[0][0], bR4);
        aR       = MFMA_F16(A1, Bf[0][1], aR);
        f32x4 aN = MFMA_F16(A0, Bf[2][0], bN4);
        aN       = MFMA_F16(A1, Bf[2][1], aN);
        f32x4 aZ = MFMA_F16(A0, Bf[1][0], bZ4);
        aZ       = MFMA_F16(A1, Bf[1][1], aZ);

        const int nxt = cur ^ 1;
        short* wh = (short*)hbuf + nxt * 1024 + cw * 512 + qd * 128 + jw;

        #pragma unroll
        for (int p = 0; p < 2; ++p) {
            const int reg = rb + p;          // wave-uniform
            float aRp = aR[reg], aZp = aZ[reg], aNp = aN[reg];
            float xv  = xv2[p];
            float hp  = hD[p];

            float ar = __builtin_fmaf(xv, wr2, aRp);
            float Er = __builtin_amdgcn_exp2f(ar);
            float DR = Er + 1.0f;
            float r  = __builtin_amdgcn_rcpf(DR);        // sigmoid(pre_r)
            float az = __builtin_fmaf(xv, wz2, aZp);
            float Ez = __builtin_amdgcn_exp2f(az);
            float DZ = Ez + 1.0f;
            float xn = __builtin_fmaf(xv, wn2, bihn2);
            float an = __builtin_fmaf(r, aNp, xn);
            float En = __builtin_amdgcn_exp2f(an);
            float DN = En + 1.0f;
            float PD = DZ * DN;                          // <= 2^40, no overflow
            float iq = __builtin_amdgcn_rcpf(PD);
            float z  = iq * DN;                          // = 1/DZ = sigmoid(pre_z)
            float rn = iq * DZ;                          // = 1/DN
            float n  = __builtin_fmaf(-2.0f, rn, 1.0f);  // tanh
            float hn = __builtin_fmaf(z, hp - n, n);     // (1-z)n + z h

            hD[p] = hn;
            wh[(m0 + p) * 8] = __builtin_bit_cast(short, (_Float16)hn);
        }
    };

    for (int t = 0; t < TT; t += 2) {
        step(0, t);
        step(1, t + 1);
    }

    // ---- epilogue: out[b] = sum_q h[b][q]*Wout[q] + bout ----
    if (tid < 128) ((float*)outp)[tid] = 0.0f;
    float p0 = hD[0] * wo;
    float p1 = hD[1] * wo;
    #pragma unroll
    for (int mask = 1; mask <= 8; mask <<= 1) {
        p0 += __shfl_xor(p0, mask, 64);
        p1 += __shfl_xor(p1, mask, 64);
    }
    __syncthreads();
    if (n16 == 0) {
        outp[wv][m0]     = p0;
        outp[wv][m0 + 1] = p1;
    }
    __syncthreads();
    if (tid < BT) {
        float s = bout[0];
        #pragma unroll
        for (int wsum = 0; wsum < 8; ++wsum) s += outp[wsum][tid];
        out[b0 + tid] = s;
    }
}

extern "C" void kernel_launch(void* const* d_in, const int* in_sizes, int n_in,
                              void* d_out, int out_size, void* d_ws, size_t ws_size,
                              hipStream_t stream) {
    (void)in_sizes; (void)n_in; (void)d_ws; (void)ws_size; (void)out_size;
    const float* x    = (const float*)d_in[0];
    const float* Wih  = (const float*)d_in[1];
    const float* Whh  = (const float*)d_in[2];
    const float* bih  = (const float*)d_in[3];
    const float* bhh  = (const float*)d_in[4];
    const float* Wout = (const float*)d_in[5];
    const float* bout = (const float*)d_in[6];
    float* out = (float*)d_out;

    gru_scan_kernel<<<dim3(4096 / BT), dim3(512), 0, stream>>>(
        x, Wih, Whh, bih, bhh, Wout, bout, out);
}